// Round 13
// baseline (178.809 us; speedup 1.0000x reference)
//
#include <hip/hip_runtime.h>

namespace {

constexpr int kN = 2048;
constexpr int kWords = kN / 64;   // 32
constexpr int kC1 = 256;          // HEADS*HID
constexpr int kC2 = 64;           // OUT_CH
constexpr int kIN = 512;
constexpr float kNegSlope = 0.2f;
constexpr float kLnEps = 1e-5f;

__device__ __forceinline__ float leakyf(float v) {
  return v >= 0.f ? v : kNegSlope * v;
}
__device__ __forceinline__ void onl(float& m, float& l, float v) {
  if (v > m) { l = l * __expf(m - v) + 1.f; m = v; }
  else       { l += __expf(v - m); }
}
__device__ __forceinline__ void mergeml(float& M, float& L, float m, float l) {
  if (m > M) { L = L * __expf(M - m) + l; M = m; }
  else       { L += l * __expf(m - M); }
}

// ---------------- adjacency bitsets ----------------
__global__ void build_bits(const int* __restrict__ ei, int E,
                           unsigned long long* rowbits, unsigned long long* colbitsT) {
  int e = blockIdx.x * 256 + threadIdx.x;
  if (e >= E) return;
  int s = ei[e], d = ei[E + e];
  atomicOr(&rowbits[(size_t)s * kWords + (d >> 6)], 1ull << (d & 63));
  atomicOr(&colbitsT[(size_t)(s >> 6) * kN + d], 1ull << (s & 63));
}

// Tiled popcount-GEMM: A2[s][d] = popc(row_s & col_d) for a 64x64 tile.
// Also emits colbits2T structure words (tile exclusively owns them).
__global__ __launch_bounds__(256) void a2_tiled(
    const unsigned long long* __restrict__ rowbits,
    const unsigned long long* __restrict__ colbitsT,
    unsigned short* __restrict__ A2,
    unsigned long long* __restrict__ colbits2T) {
  int bx = blockIdx.x, by = blockIdx.y;   // d-tile, s-tile
  int t = threadIdx.x;
  __shared__ unsigned long long rb[64][33];  // padded: conflict-free
  __shared__ unsigned long long cb[32][64];
  __shared__ unsigned long long cw[64];
  int s0 = by * 64, d0 = bx * 64;
  for (int i = t; i < 64 * 32; i += 256) {
    int ss = i >> 5, w = i & 31;
    rb[ss][w] = rowbits[(size_t)(s0 + ss) * kWords + w];
  }
  for (int i = t; i < 32 * 64; i += 256) {
    int w = i >> 6, dd = i & 63;
    cb[w][dd] = colbitsT[(size_t)w * kN + d0 + dd];
  }
  if (t < 64) cw[t] = 0ull;
  __syncthreads();
  int tx = t & 15, ty4 = (t >> 4) * 4;
  int acc[4][4] = {};
#pragma unroll 4
  for (int w = 0; w < 32; ++w) {
    unsigned long long r0 = rb[ty4 + 0][w], r1 = rb[ty4 + 1][w];
    unsigned long long r2 = rb[ty4 + 2][w], r3 = rb[ty4 + 3][w];
    unsigned long long c0 = cb[w][tx], c1 = cb[w][tx + 16];
    unsigned long long c2 = cb[w][tx + 32], c3 = cb[w][tx + 48];
    acc[0][0] += __popcll(r0 & c0); acc[0][1] += __popcll(r0 & c1);
    acc[0][2] += __popcll(r0 & c2); acc[0][3] += __popcll(r0 & c3);
    acc[1][0] += __popcll(r1 & c0); acc[1][1] += __popcll(r1 & c1);
    acc[1][2] += __popcll(r1 & c2); acc[1][3] += __popcll(r1 & c3);
    acc[2][0] += __popcll(r2 & c0); acc[2][1] += __popcll(r2 & c1);
    acc[2][2] += __popcll(r2 & c2); acc[2][3] += __popcll(r2 & c3);
    acc[3][0] += __popcll(r3 & c0); acc[3][1] += __popcll(r3 & c1);
    acc[3][2] += __popcll(r3 & c2); acc[3][3] += __popcll(r3 & c3);
  }
#pragma unroll
  for (int i = 0; i < 4; ++i)
#pragma unroll
    for (int j = 0; j < 4; ++j)
      A2[(size_t)(s0 + ty4 + i) * kN + d0 + tx + 16 * j] = (unsigned short)acc[i][j];
#pragma unroll
  for (int j = 0; j < 4; ++j) {
    unsigned long long m = 0;
#pragma unroll
    for (int i = 0; i < 4; ++i)
      if (acc[i][j]) m |= 1ull << (ty4 + i);
    if (m) atomicOr(&cw[tx + 16 * j], m);
  }
  __syncthreads();
  if (t < 64) colbits2T[(size_t)by * kN + d0 + t] = cw[t];
}

// A3 row s = sum_{j in rowA[s]} A2[j,:]: dense coalesced uint4 packed-u16
// adds. Writes unnormalized u16 A3 + 1/rowsum. One block per s.
__global__ __launch_bounds__(256) void a3_dense(
    const unsigned long long* __restrict__ rowbits,
    const unsigned short* __restrict__ A2,
    unsigned short* __restrict__ a3u,
    float* __restrict__ invr) {
  int s = blockIdx.x;
  int t = threadIdx.x;
  int lane = t & 63;
  __shared__ unsigned short jl[kN];
  __shared__ int jtot_s;
  __shared__ float redv[4];
  if (t < 64) {
    unsigned long long word = (lane < kWords) ? rowbits[(size_t)s * kWords + lane] : 0ull;
    int c = __popcll(word);
    int inc = c;
    for (int o = 1; o < 64; o <<= 1) { int v = __shfl_up(inc, o); if (lane >= o) inc += v; }
    if (lane == 63) jtot_s = inc;
    int off = inc - c;
    int base = lane * 64;
    while (word) {
      int b = __builtin_ctzll(word);
      word &= word - 1;
      jl[off++] = (unsigned short)(base + b);
    }
  }
  __syncthreads();
  int jtot = jtot_s;
  const uint4* a2v = reinterpret_cast<const uint4*>(A2);  // 256 uint4 per row
  uint4 acc = make_uint4(0u, 0u, 0u, 0u);
  int ji = 0;
  for (; ji + 4 <= jtot; ji += 4) {
    uint4 v0 = a2v[(size_t)jl[ji + 0] * 256 + t];
    uint4 v1 = a2v[(size_t)jl[ji + 1] * 256 + t];
    uint4 v2 = a2v[(size_t)jl[ji + 2] * 256 + t];
    uint4 v3 = a2v[(size_t)jl[ji + 3] * 256 + t];
    acc.x += v0.x + v1.x + v2.x + v3.x;
    acc.y += v0.y + v1.y + v2.y + v3.y;
    acc.z += v0.z + v1.z + v2.z + v3.z;
    acc.w += v0.w + v1.w + v2.w + v3.w;
  }
  for (; ji < jtot; ++ji) {
    uint4 v = a2v[(size_t)jl[ji] * 256 + t];
    acc.x += v.x; acc.y += v.y; acc.z += v.z; acc.w += v.w;
  }
  reinterpret_cast<uint4*>(a3u)[(size_t)s * 256 + t] = acc;
  float tot = (float)((acc.x & 0xffffu) + (acc.x >> 16) +
                      (acc.y & 0xffffu) + (acc.y >> 16) +
                      (acc.z & 0xffffu) + (acc.z >> 16) +
                      (acc.w & 0xffffu) + (acc.w >> 16));
  for (int o = 32; o; o >>= 1) tot += __shfl_xor(tot, o);
  if (lane == 0) redv[t >> 6] = tot;
  __syncthreads();
  if (t == 0)
    invr[s] = 1.f / fmaxf(redv[0] + redv[1] + redv[2] + redv[3], 1.f);
}

// motifT[d][s] = a3u[s][d] * invr[s]  (LDS-tiled transpose + normalize)
__global__ __launch_bounds__(256) void transpose_motif(
    const unsigned short* __restrict__ a3u, const float* __restrict__ invr,
    float* __restrict__ motifT) {
  __shared__ float tile[64][65];
  __shared__ float invs[64];
  int d0 = blockIdx.x * 64, s0 = blockIdx.y * 64;
  int t = threadIdx.x;
  int tx = t & 63, ty = t >> 6;
  if (t < 64) invs[t] = invr[s0 + t];
  __syncthreads();
#pragma unroll
  for (int i = 0; i < 64; i += 4)
    tile[ty + i][tx] = (float)a3u[(size_t)(s0 + ty + i) * kN + d0 + tx] * invs[ty + i];
  __syncthreads();
#pragma unroll
  for (int i = 0; i < 64; i += 4)
    motifT[(size_t)(d0 + ty + i) * kN + s0 + tx] = tile[tx][ty + i];
}

// layer-1 GEMM, 32x64 tiles, fused s_src/s_dst epilogue. grid (4, 64, 2)
__global__ __launch_bounds__(256) void gemm1(
    const float* __restrict__ x, const float* __restrict__ l1w,
    float* __restrict__ hx1,
    const float* __restrict__ l1as, const float* __restrict__ l1ad,
    float* __restrict__ ss1, float* __restrict__ sd1) {
  int hop = blockIdx.z;
  int row0 = blockIdx.y * 32, col0 = blockIdx.x * 64;
  const float* B = l1w + (size_t)hop * kIN * kC1;
  float* Cz = hx1 + (size_t)hop * kN * kC1;
  __shared__ float As[16][34];   // stride 34 == 2 mod 32: 2-way max (free)
  __shared__ float Bs[16][65];
  int t = threadIdx.x;
  int tx = t & 15, ty = t >> 4;  // ty in [0,16)
  float acc[2][4] = {};
  for (int k0 = 0; k0 < kIN; k0 += 16) {
    if (t < 128) {
      int m = t >> 2, kk = (t & 3) * 4;
      float4 va = *reinterpret_cast<const float4*>(x + (size_t)(row0 + m) * kIN + k0 + kk);
      As[kk + 0][m] = va.x; As[kk + 1][m] = va.y;
      As[kk + 2][m] = va.z; As[kk + 3][m] = va.w;
    }
    {
      int kb = t >> 4, nb = (t & 15) * 4;
      float4 vb = *reinterpret_cast<const float4*>(B + (size_t)(k0 + kb) * kC1 + col0 + nb);
      Bs[kb][nb + 0] = vb.x; Bs[kb][nb + 1] = vb.y;
      Bs[kb][nb + 2] = vb.z; Bs[kb][nb + 3] = vb.w;
    }
    __syncthreads();
#pragma unroll
    for (int kk2 = 0; kk2 < 16; ++kk2) {
      float a0 = As[kk2][ty * 2 + 0];
      float a1 = As[kk2][ty * 2 + 1];
      float b[4];
#pragma unroll
      for (int j = 0; j < 4; ++j) b[j] = Bs[kk2][tx * 4 + j];
#pragma unroll
      for (int j = 0; j < 4; ++j) {
        acc[0][j] += a0 * b[j];
        acc[1][j] += a1 * b[j];
      }
    }
    __syncthreads();
  }
#pragma unroll
  for (int i = 0; i < 2; ++i)
#pragma unroll
    for (int j = 0; j < 4; ++j)
      Cz[(size_t)(row0 + ty * 2 + i) * kC1 + col0 + tx * 4 + j] = acc[i][j];
  int h = col0 >> 6;
  float as_[4], ad_[4];
#pragma unroll
  for (int j = 0; j < 4; ++j) {
    as_[j] = l1as[hop * kC1 + col0 + tx * 4 + j];
    ad_[j] = l1ad[hop * kC1 + col0 + tx * 4 + j];
  }
#pragma unroll
  for (int i = 0; i < 2; ++i) {
    float ps = acc[i][0] * as_[0] + acc[i][1] * as_[1] +
               acc[i][2] * as_[2] + acc[i][3] * as_[3];
    float pd = acc[i][0] * ad_[0] + acc[i][1] * ad_[1] +
               acc[i][2] * ad_[2] + acc[i][3] * ad_[3];
#pragma unroll
    for (int o = 1; o < 16; o <<= 1) {
      ps += __shfl_xor(ps, o);
      pd += __shfl_xor(pd, o);
    }
    if (tx == 0) {
      int n = row0 + ty * 2 + i;
      ss1[((size_t)hop * kN + n) * 4 + h] = ps;
      sd1[((size_t)hop * kN + n) * 4 + h] = pd;
    }
  }
}

// layer-2 GEMM, 16x64 tiles (z: 0,1 = hops + src/dst epilogue; 2 = res).
// grid (1, 128, 3)
__global__ __launch_bounds__(256) void gemm2(
    const float* __restrict__ A, const float* __restrict__ l2w,
    const float* __restrict__ l2rw, float* __restrict__ C,
    const float* __restrict__ attS, const float* __restrict__ attD,
    float* __restrict__ ssO, float* __restrict__ sdO) {
  int z = blockIdx.z;
  const float* B = (z < 2) ? l2w + (size_t)z * kC1 * kC2 : l2rw;
  float* Cz = C + (size_t)z * kN * kC2;
  __shared__ float As[16][34];
  __shared__ float Bs[16][65];
  int t = threadIdx.x;
  int tx = t & 15, ty = t >> 4;  // ty in [0,16) = row
  int row0 = blockIdx.y * 16;
  float acc[4] = {};
  for (int k0 = 0; k0 < kC1; k0 += 16) {
    if (t < 64) {
      int m = t >> 2, kk = (t & 3) * 4;
      float4 va = *reinterpret_cast<const float4*>(A + (size_t)(row0 + m) * kC1 + k0 + kk);
      As[kk + 0][m] = va.x; As[kk + 1][m] = va.y;
      As[kk + 2][m] = va.z; As[kk + 3][m] = va.w;
    }
    {
      int kb = t >> 4, nb = (t & 15) * 4;
      float4 vb = *reinterpret_cast<const float4*>(B + (size_t)(k0 + kb) * kC2 + nb);
      Bs[kb][nb + 0] = vb.x; Bs[kb][nb + 1] = vb.y;
      Bs[kb][nb + 2] = vb.z; Bs[kb][nb + 3] = vb.w;
    }
    __syncthreads();
#pragma unroll
    for (int kk2 = 0; kk2 < 16; ++kk2) {
      float a = As[kk2][ty];
#pragma unroll
      for (int j = 0; j < 4; ++j) acc[j] += a * Bs[kk2][tx * 4 + j];
    }
    __syncthreads();
  }
#pragma unroll
  for (int j = 0; j < 4; ++j)
    Cz[(size_t)(row0 + ty) * kC2 + tx * 4 + j] = acc[j];
  if (z < 2) {
    float as_[4], ad_[4];
#pragma unroll
    for (int j = 0; j < 4; ++j) {
      as_[j] = attS[z * kC2 + tx * 4 + j];
      ad_[j] = attD[z * kC2 + tx * 4 + j];
    }
    float ps = acc[0] * as_[0] + acc[1] * as_[1] + acc[2] * as_[2] + acc[3] * as_[3];
    float pd = acc[0] * ad_[0] + acc[1] * ad_[1] + acc[2] * ad_[2] + acc[3] * ad_[3];
#pragma unroll
    for (int o = 1; o < 16; o <<= 1) {
      ps += __shfl_xor(ps, o);
      pd += __shfl_xor(pd, o);
    }
    if (tx == 0) {
      int n = row0 + ty;
      ssO[(size_t)z * kN + n] = ps;
      sdO[(size_t)z * kN + n] = pd;
    }
  }
}

// layer-1 aggregation, fused stats; motifT row staged in LDS.
__global__ __launch_bounds__(256) void agg_l1(
    const float* __restrict__ hx,      // [2][N][256]
    const float* __restrict__ ssrc,    // [2][N][4]
    const float* __restrict__ sdst,    // [2][N][4]
    const float* __restrict__ motifT,  // [N(d)][N(s)]
    const unsigned long long* __restrict__ colbitsT,
    const unsigned long long* __restrict__ colbits2T,
    const float* __restrict__ hop_att,
    const float* __restrict__ bias,
    float* __restrict__ hbuf) {
  int d = blockIdx.x;
  int t = threadIdx.x;
  int lane = t & 63;
  int h = t >> 6;       // stats wave == head; also s-slot for FMA
  int cq = lane;        // channel quad [0,64)
  int hq = cq >> 4;     // head of this quad
  __shared__ unsigned short slist[kN];
  __shared__ float mrow[kN];
  __shared__ float w_lds[64 * 4];
  __shared__ int s_total;
  __shared__ float4 red4[4][64];
  {
    const float4* mp = reinterpret_cast<const float4*>(motifT + (size_t)d * kN);
    float4* mr = reinterpret_cast<float4*>(mrow);
    mr[t] = mp[t];
    mr[t + 256] = mp[t + 256];
  }
  float a0 = hop_att[0], a1 = hop_att[1];
  float mxa = fmaxf(a0, a1);
  float e0 = __expf(a0 - mxa), e1 = __expf(a1 - mxa);
  float wh0 = e0 / (e0 + e1), wh1 = e1 / (e0 + e1);
  float4 acc4 = make_float4(0.f, 0.f, 0.f, 0.f);
  for (int hop = 0; hop < 2; ++hop) {
    const unsigned long long* cm = hop ? colbits2T : colbitsT;
    if (t < 64) {
      unsigned long long word = (lane < kWords) ? cm[(size_t)lane * kN + d] : 0ull;
      if (lane == (d >> 6)) word |= 1ull << (d & 63);
      int cnt = __popcll(word);
      int inc = cnt;
      for (int o = 1; o < 64; o <<= 1) { int v = __shfl_up(inc, o); if (lane >= o) inc += v; }
      if (lane == 63) s_total = inc;
      int off = inc - cnt;
      int base = lane * 64;
      while (word) {
        int b = __builtin_ctzll(word);
        word &= word - 1;
        slist[off++] = (unsigned short)(base + b);
      }
    }
    __syncthreads();
    int total = s_total;
    float sd = sdst[((size_t)hop * kN + d) * 4 + h];
    const float4* hx4 = reinterpret_cast<const float4*>(hx + (size_t)hop * kN * kC1);
    const float* ssp = ssrc + (size_t)hop * kN * 4;
    float m1 = -3.0e38f, l1v = 0.f, m2 = -3.0e38f, l2v = 0.f;
    for (int q = lane; q < total; q += 64) {
      int s = slist[q];
      float mv = mrow[s];
      float v = ssp[s * 4 + h] + sd;
      onl(m1, l1v, leakyf(v));
      onl(m2, l2v, leakyf(v * mv));
    }
#pragma unroll
    for (int o = 1; o < 64; o <<= 1) {
      float mm = __shfl_xor(m1, o), ll = __shfl_xor(l1v, o);
      mergeml(m1, l1v, mm, ll);
      float mm2 = __shfl_xor(m2, o), ll2 = __shfl_xor(l2v, o);
      mergeml(m2, l2v, mm2, ll2);
    }
    float il1 = 1.f / l1v, il2 = 1.f / l2v;
    float wh = hop ? wh1 : wh0;
    for (int c0 = 0; c0 < total; c0 += 64) {
      int nsi = min(64, total - c0);
      if (lane < nsi) {
        int s = slist[c0 + lane];
        float mv = mrow[s];
        float v = ssp[s * 4 + h] + sd;
        w_lds[lane * 4 + h] = (0.5f * __expf(leakyf(v) - m1) * il1 +
                               0.5f * __expf(leakyf(v * mv) - m2) * il2) * wh;
      }
      __syncthreads();
      int q = h;
      for (; q + 4 < nsi; q += 8) {
        int s0 = slist[c0 + q], s1 = slist[c0 + q + 4];
        float4 r0 = hx4[(size_t)s0 * 64 + cq];
        float4 r1 = hx4[(size_t)s1 * 64 + cq];
        float w0 = w_lds[q * 4 + hq], w1 = w_lds[(q + 4) * 4 + hq];
        acc4.x += w0 * r0.x + w1 * r1.x;
        acc4.y += w0 * r0.y + w1 * r1.y;
        acc4.z += w0 * r0.z + w1 * r1.z;
        acc4.w += w0 * r0.w + w1 * r1.w;
      }
      if (q < nsi) {
        int s0 = slist[c0 + q];
        float4 r0 = hx4[(size_t)s0 * 64 + cq];
        float w0 = w_lds[q * 4 + hq];
        acc4.x += w0 * r0.x; acc4.y += w0 * r0.y;
        acc4.z += w0 * r0.z; acc4.w += w0 * r0.w;
      }
      __syncthreads();
    }
    __syncthreads();
  }
  red4[h][cq] = acc4;
  __syncthreads();
  if (t < 64) {
    float4 a = red4[0][t], b = red4[1][t], c = red4[2][t], e = red4[3][t];
    float4 bv = reinterpret_cast<const float4*>(bias)[t];
    float4 v;
    v.x = a.x + b.x + c.x + e.x + bv.x;
    v.y = a.y + b.y + c.y + e.y + bv.y;
    v.z = a.z + b.z + c.z + e.z + bv.z;
    v.w = a.w + b.w + c.w + e.w + bv.w;
    v.x = v.x > 0.f ? v.x : __expf(v.x) - 1.f;
    v.y = v.y > 0.f ? v.y : __expf(v.y) - 1.f;
    v.z = v.z > 0.f ? v.z : __expf(v.z) - 1.f;
    v.w = v.w > 0.f ? v.w : __expf(v.w) - 1.f;
    reinterpret_cast<float4*>(hbuf)[(size_t)d * 64 + t] = v;
  }
}

// layer-2 aggregation, fused stats; motifT row staged in LDS;
// fused residual + LayerNorm + bias -> output. grid = N.
__global__ __launch_bounds__(256) void agg_l2(
    const float* __restrict__ hx,      // [2][N][64]
    const float* __restrict__ ssrc,    // [2][N]
    const float* __restrict__ sdst,    // [2][N]
    const float* __restrict__ motifT,
    const unsigned long long* __restrict__ colbitsT,
    const unsigned long long* __restrict__ colbits2T,
    const float* __restrict__ hop_att,
    const float* __restrict__ res,     // [N][64]
    const float* __restrict__ lns, const float* __restrict__ lnb,
    const float* __restrict__ l2b,
    float* __restrict__ out) {
  int d = blockIdx.x;
  int t = threadIdx.x;
  int lane = t & 63;
  int g = t >> 6;      // wave id (stats)
  int cq = t & 15;     // channel quad [0,16)
  int sg = t >> 4;     // s-slot [0,16)
  __shared__ unsigned short slist[kN];
  __shared__ float mrow[kN];
  __shared__ float w_lds[64];
  __shared__ int s_total;
  __shared__ float4 red4[16][16];
  __shared__ float out_lds[64];
  __shared__ float smst[4][4];
  {
    const float4* mp = reinterpret_cast<const float4*>(motifT + (size_t)d * kN);
    float4* mr = reinterpret_cast<float4*>(mrow);
    mr[t] = mp[t];
    mr[t + 256] = mp[t + 256];
  }
  float a0 = hop_att[0], a1 = hop_att[1];
  float mxa = fmaxf(a0, a1);
  float e0 = __expf(a0 - mxa), e1 = __expf(a1 - mxa);
  float wh0 = e0 / (e0 + e1), wh1 = e1 / (e0 + e1);
  float4 acc4 = make_float4(0.f, 0.f, 0.f, 0.f);
  for (int hop = 0; hop < 2; ++hop) {
    const unsigned long long* cm = hop ? colbits2T : colbitsT;
    if (t < 64) {
      unsigned long long word = (lane < kWords) ? cm[(size_t)lane * kN + d] : 0ull;
      if (lane == (d >> 6)) word |= 1ull << (d & 63);
      int cnt = __popcll(word);
      int inc = cnt;
      for (int o = 1; o < 64; o <<= 1) { int v = __shfl_up(inc, o); if (lane >= o) inc += v; }
      if (lane == 63) s_total = inc;
      int off = inc - cnt;
      int base = lane * 64;
      while (word) {
        int b = __builtin_ctzll(word);
        word &= word - 1;
        slist[off++] = (unsigned short)(base + b);
      }
    }
    __syncthreads();
    int total = s_total;
    float sd = sdst[(size_t)hop * kN + d];
    const float4* hx4 = reinterpret_cast<const float4*>(hx + (size_t)hop * kN * kC2);
    const float* ssp = ssrc + (size_t)hop * kN;
    float m1 = -3.0e38f, l1v = 0.f, m2 = -3.0e38f, l2v = 0.f;
    for (int q = t; q < total; q += 256) {
      int s = slist[q];
      float mv = mrow[s];
      float v = ssp[s] + sd;
      onl(m1, l1v, leakyf(v));
      onl(m2, l2v, leakyf(v * mv));
    }
#pragma unroll
    for (int o = 1; o < 64; o <<= 1) {
      float mm = __shfl_xor(m1, o), ll = __shfl_xor(l1v, o);
      mergeml(m1, l1v, mm, ll);
      float mm2 = __shfl_xor(m2, o), ll2 = __shfl_xor(l2v, o);
      mergeml(m2, l2v, mm2, ll2);
    }
    if (lane == 0) {
      smst[g][0] = m1; smst[g][1] = l1v; smst[g][2] = m2; smst[g][3] = l2v;
    }
    __syncthreads();
    float M1 = -3.0e38f, L1 = 0.f, M2 = -3.0e38f, L2 = 0.f;
#pragma unroll
    for (int gg = 0; gg < 4; ++gg) {
      mergeml(M1, L1, smst[gg][0], smst[gg][1]);
      mergeml(M2, L2, smst[gg][2], smst[gg][3]);
    }
    float il1 = 1.f / L1, il2 = 1.f / L2;
    float wh = hop ? wh1 : wh0;
    for (int c0 = 0; c0 < total; c0 += 64) {
      int nsi = min(64, total - c0);
      if (t < nsi) {
        int s = slist[c0 + t];
        float mv = mrow[s];
        float v = ssp[s] + sd;
        w_lds[t] = (0.5f * __expf(leakyf(v) - M1) * il1 +
                    0.5f * __expf(leakyf(v * mv) - M2) * il2) * wh;
      }
      __syncthreads();
      int q = sg;
      for (; q + 16 < nsi; q += 32) {
        int s0 = slist[c0 + q], s1 = slist[c0 + q + 16];
        float4 r0 = hx4[(size_t)s0 * 16 + cq];
        float4 r1 = hx4[(size_t)s1 * 16 + cq];
        float w0 = w_lds[q], w1 = w_lds[q + 16];
        acc4.x += w0 * r0.x + w1 * r1.x;
        acc4.y += w0 * r0.y + w1 * r1.y;
        acc4.z += w0 * r0.z + w1 * r1.z;
        acc4.w += w0 * r0.w + w1 * r1.w;
      }
      if (q < nsi) {
        int s0 = slist[c0 + q];
        float4 r0 = hx4[(size_t)s0 * 16 + cq];
        float w0 = w_lds[q];
        acc4.x += w0 * r0.x; acc4.y += w0 * r0.y;
        acc4.z += w0 * r0.z; acc4.w += w0 * r0.w;
      }
      __syncthreads();
    }
    __syncthreads();
  }
  red4[sg][cq] = acc4;
  __syncthreads();
  if (t < 16) {
    float4 v = make_float4(0.f, 0.f, 0.f, 0.f);
#pragma unroll
    for (int q = 0; q < 16; ++q) {
      float4 a = red4[q][t];
      v.x += a.x; v.y += a.y; v.z += a.z; v.w += a.w;
    }
    out_lds[t * 4 + 0] = v.x;
    out_lds[t * 4 + 1] = v.y;
    out_lds[t * 4 + 2] = v.z;
    out_lds[t * 4 + 3] = v.w;
  }
  __syncthreads();
  if (t < 64) {
    float v = out_lds[t] + res[(size_t)d * kC2 + t];
    float s = v;
    for (int o = 32; o; o >>= 1) s += __shfl_xor(s, o);
    float mu = s * (1.f / kC2);
    float dv = v - mu;
    float q = dv * dv;
    for (int o = 32; o; o >>= 1) q += __shfl_xor(q, o);
    float var = q * (1.f / kC2);
    out[(size_t)d * kC2 + t] = dv * rsqrtf(var + kLnEps) * lns[t] + lnb[t] + l2b[t];
  }
}

}  // namespace

extern "C" void kernel_launch(void* const* d_in, const int* in_sizes, int n_in,
                              void* d_out, int out_size, void* d_ws, size_t ws_size,
                              hipStream_t stream) {
  const float* x    = (const float*)d_in[0];
  const int*   ei   = (const int*)d_in[1];
  const float* l1w  = (const float*)d_in[2];
  const float* l1as = (const float*)d_in[3];
  const float* l1ad = (const float*)d_in[4];
  const float* l1ha = (const float*)d_in[5];
  const float* l1b  = (const float*)d_in[6];
  const float* l2w  = (const float*)d_in[7];
  const float* l2as = (const float*)d_in[8];
  const float* l2ad = (const float*)d_in[9];
  const float* l2ha = (const float*)d_in[10];
  const float* l2rw = (const float*)d_in[11];
  const float* lns  = (const float*)d_in[12];
  const float* lnb  = (const float*)d_in[13];
  const float* l2b  = (const float*)d_in[14];
  int E = in_sizes[1] / 2;

  // ---- workspace layout (bytes) ----
  size_t o = 0;
  auto take = [&](size_t bytes) { size_t r = o; o += (bytes + 255) & ~(size_t)255; return r; };
  size_t oRB  = take((size_t)kN * kWords * 8);      // rowbits (zeroed)
  size_t oCB  = take((size_t)kWords * kN * 8);      // colbitsT (zeroed)
  size_t zEnd = o;                                  // zero region end
  size_t oCB2 = take((size_t)kWords * kN * 8);      // colbits2T (fully written)
  size_t oA2  = take((size_t)kN * kN * 2);          // dense A2 u16
  size_t oA3  = take((size_t)kN * kN * 2);          // dense A3 u16 (unnormalized)
  size_t oINV = take((size_t)kN * 4);               // 1/rowsum
  size_t oMFT = take((size_t)kN * kN * 4);          // motifT f32
  size_t oHX1 = take((size_t)2 * kN * kC1 * 4);
  size_t oH   = take((size_t)kN * kC1 * 4);
  size_t oHX2 = take((size_t)3 * kN * kC2 * 4);     // hop0 | hop1 | res
  size_t oSS1 = take((size_t)2 * kN * 4 * 4);
  size_t oSD1 = take((size_t)2 * kN * 4 * 4);
  size_t oSS2 = take((size_t)2 * kN * 4);
  size_t oSD2 = take((size_t)2 * kN * 4);
  if (ws_size < o) return;  // insufficient scratch; fail visibly

  char* w = (char*)d_ws;
  unsigned long long* rowbits = (unsigned long long*)(w + oRB);
  unsigned long long* colbitsT = (unsigned long long*)(w + oCB);
  unsigned long long* colbits2T = (unsigned long long*)(w + oCB2);
  unsigned short* A2 = (unsigned short*)(w + oA2);
  unsigned short* A3u = (unsigned short*)(w + oA3);
  float* invr = (float*)(w + oINV);
  float* motifT = (float*)(w + oMFT);
  float* hx1 = (float*)(w + oHX1);
  float* hbuf = (float*)(w + oH);
  float* hx2 = (float*)(w + oHX2);
  float* res = hx2 + (size_t)2 * kN * kC2;
  float* ss1 = (float*)(w + oSS1);
  float* sd1 = (float*)(w + oSD1);
  float* ss2 = (float*)(w + oSS2);
  float* sd2 = (float*)(w + oSD2);

  hipMemsetAsync(d_ws, 0, zEnd, stream);

  build_bits<<<(E + 255) / 256, 256, 0, stream>>>(ei, E, rowbits, colbitsT);
  a2_tiled<<<dim3(kN / 64, kN / 64), 256, 0, stream>>>(rowbits, colbitsT, A2, colbits2T);
  a3_dense<<<kN, 256, 0, stream>>>(rowbits, A2, A3u, invr);
  transpose_motif<<<dim3(kN / 64, kN / 64), 256, 0, stream>>>(A3u, invr, motifT);

  gemm1<<<dim3(kC1 / 64, kN / 32, 2), 256, 0, stream>>>(x, l1w, hx1, l1as, l1ad, ss1, sd1);
  agg_l1<<<kN, 256, 0, stream>>>(hx1, ss1, sd1, motifT, colbitsT, colbits2T,
                                 l1ha, l1b, hbuf);

  gemm2<<<dim3(1, kN / 16, 3), 256, 0, stream>>>(hbuf, l2w, l2rw, hx2,
                                                 l2as, l2ad, ss2, sd2);
  agg_l2<<<kN, 256, 0, stream>>>(hx2, ss2, sd2, motifT, colbitsT, colbits2T,
                                 l2ha, res, lns, lnb, l2b, (float*)d_out);
}

// Round 14
// 147.810 us; speedup vs baseline: 1.2097x; 1.2097x over previous
//
#include <hip/hip_runtime.h>

namespace {

constexpr int kN = 2048;
constexpr int kWords = kN / 64;   // 32
constexpr int kC1 = 256;          // HEADS*HID
constexpr int kC2 = 64;           // OUT_CH
constexpr int kIN = 512;
constexpr float kNegSlope = 0.2f;
constexpr float kLnEps = 1e-5f;

__device__ __forceinline__ float leakyf(float v) {
  return v >= 0.f ? v : kNegSlope * v;
}
__device__ __forceinline__ void onl(float& m, float& l, float v) {
  if (v > m) { l = l * __expf(m - v) + 1.f; m = v; }
  else       { l += __expf(v - m); }
}
__device__ __forceinline__ void mergeml(float& M, float& L, float m, float l) {
  if (m > M) { L = L * __expf(M - m) + l; M = m; }
  else       { L += l * __expf(m - M); }
}

// ---------------- adjacency bitsets ----------------
__global__ void build_bits(const int* __restrict__ ei, int E,
                           unsigned long long* rowbits, unsigned long long* colbitsT) {
  int e = blockIdx.x * 256 + threadIdx.x;
  if (e >= E) return;
  int s = ei[e], d = ei[E + e];
  atomicOr(&rowbits[(size_t)s * kWords + (d >> 6)], 1ull << (d & 63));
  atomicOr(&colbitsT[(size_t)(s >> 6) * kN + d], 1ull << (s & 63));
}

// Tiled popcount-GEMM: A2[s][d] = popc(row_s & col_d) for a 64x64 tile.
// Also emits colbits2T structure words (tile exclusively owns them).
__global__ __launch_bounds__(256) void a2_tiled(
    const unsigned long long* __restrict__ rowbits,
    const unsigned long long* __restrict__ colbitsT,
    unsigned short* __restrict__ A2,
    unsigned long long* __restrict__ colbits2T) {
  int bx = blockIdx.x, by = blockIdx.y;   // d-tile, s-tile
  int t = threadIdx.x;
  __shared__ unsigned long long rb[64][33];  // padded: conflict-free
  __shared__ unsigned long long cb[32][64];
  __shared__ unsigned long long cw[64];
  int s0 = by * 64, d0 = bx * 64;
  for (int i = t; i < 64 * 32; i += 256) {
    int ss = i >> 5, w = i & 31;
    rb[ss][w] = rowbits[(size_t)(s0 + ss) * kWords + w];
  }
  for (int i = t; i < 32 * 64; i += 256) {
    int w = i >> 6, dd = i & 63;
    cb[w][dd] = colbitsT[(size_t)w * kN + d0 + dd];
  }
  if (t < 64) cw[t] = 0ull;
  __syncthreads();
  int tx = t & 15, ty4 = (t >> 4) * 4;
  int acc[4][4] = {};
#pragma unroll 4
  for (int w = 0; w < 32; ++w) {
    unsigned long long r0 = rb[ty4 + 0][w], r1 = rb[ty4 + 1][w];
    unsigned long long r2 = rb[ty4 + 2][w], r3 = rb[ty4 + 3][w];
    unsigned long long c0 = cb[w][tx], c1 = cb[w][tx + 16];
    unsigned long long c2 = cb[w][tx + 32], c3 = cb[w][tx + 48];
    acc[0][0] += __popcll(r0 & c0); acc[0][1] += __popcll(r0 & c1);
    acc[0][2] += __popcll(r0 & c2); acc[0][3] += __popcll(r0 & c3);
    acc[1][0] += __popcll(r1 & c0); acc[1][1] += __popcll(r1 & c1);
    acc[1][2] += __popcll(r1 & c2); acc[1][3] += __popcll(r1 & c3);
    acc[2][0] += __popcll(r2 & c0); acc[2][1] += __popcll(r2 & c1);
    acc[2][2] += __popcll(r2 & c2); acc[2][3] += __popcll(r2 & c3);
    acc[3][0] += __popcll(r3 & c0); acc[3][1] += __popcll(r3 & c1);
    acc[3][2] += __popcll(r3 & c2); acc[3][3] += __popcll(r3 & c3);
  }
#pragma unroll
  for (int i = 0; i < 4; ++i)
#pragma unroll
    for (int j = 0; j < 4; ++j)
      A2[(size_t)(s0 + ty4 + i) * kN + d0 + tx + 16 * j] = (unsigned short)acc[i][j];
#pragma unroll
  for (int j = 0; j < 4; ++j) {
    unsigned long long m = 0;
#pragma unroll
    for (int i = 0; i < 4; ++i)
      if (acc[i][j]) m |= 1ull << (ty4 + i);
    if (m) atomicOr(&cw[tx + 16 * j], m);
  }
  __syncthreads();
  if (t < 64) colbits2T[(size_t)by * kN + d0 + t] = cw[t];
}

// A3 row s = sum_{j in rowA[s]} A2[j,:]: dense coalesced uint4 packed-u16
// adds. Writes unnormalized u16 A3 + 1/rowsum. One block per s.
__global__ __launch_bounds__(256) void a3_dense(
    const unsigned long long* __restrict__ rowbits,
    const unsigned short* __restrict__ A2,
    unsigned short* __restrict__ a3u,
    float* __restrict__ invr) {
  int s = blockIdx.x;
  int t = threadIdx.x;
  int lane = t & 63;
  __shared__ unsigned short jl[kN];
  __shared__ int jtot_s;
  __shared__ float redv[4];
  if (t < 64) {
    unsigned long long word = (lane < kWords) ? rowbits[(size_t)s * kWords + lane] : 0ull;
    int c = __popcll(word);
    int inc = c;
    for (int o = 1; o < 64; o <<= 1) { int v = __shfl_up(inc, o); if (lane >= o) inc += v; }
    if (lane == 63) jtot_s = inc;
    int off = inc - c;
    int base = lane * 64;
    while (word) {
      int b = __builtin_ctzll(word);
      word &= word - 1;
      jl[off++] = (unsigned short)(base + b);
    }
  }
  __syncthreads();
  int jtot = jtot_s;
  const uint4* a2v = reinterpret_cast<const uint4*>(A2);  // 256 uint4 per row
  uint4 acc = make_uint4(0u, 0u, 0u, 0u);
  int ji = 0;
  for (; ji + 4 <= jtot; ji += 4) {
    uint4 v0 = a2v[(size_t)jl[ji + 0] * 256 + t];
    uint4 v1 = a2v[(size_t)jl[ji + 1] * 256 + t];
    uint4 v2 = a2v[(size_t)jl[ji + 2] * 256 + t];
    uint4 v3 = a2v[(size_t)jl[ji + 3] * 256 + t];
    acc.x += v0.x + v1.x + v2.x + v3.x;
    acc.y += v0.y + v1.y + v2.y + v3.y;
    acc.z += v0.z + v1.z + v2.z + v3.z;
    acc.w += v0.w + v1.w + v2.w + v3.w;
  }
  for (; ji < jtot; ++ji) {
    uint4 v = a2v[(size_t)jl[ji] * 256 + t];
    acc.x += v.x; acc.y += v.y; acc.z += v.z; acc.w += v.w;
  }
  reinterpret_cast<uint4*>(a3u)[(size_t)s * 256 + t] = acc;
  float tot = (float)((acc.x & 0xffffu) + (acc.x >> 16) +
                      (acc.y & 0xffffu) + (acc.y >> 16) +
                      (acc.z & 0xffffu) + (acc.z >> 16) +
                      (acc.w & 0xffffu) + (acc.w >> 16));
  for (int o = 32; o; o >>= 1) tot += __shfl_xor(tot, o);
  if (lane == 0) redv[t >> 6] = tot;
  __syncthreads();
  if (t == 0)
    invr[s] = 1.f / fmaxf(redv[0] + redv[1] + redv[2] + redv[3], 1.f);
}

// motifT[d][s] = a3u[s][d] * invr[s]  (LDS-tiled transpose + normalize)
__global__ __launch_bounds__(256) void transpose_motif(
    const unsigned short* __restrict__ a3u, const float* __restrict__ invr,
    float* __restrict__ motifT) {
  __shared__ float tile[64][65];
  __shared__ float invs[64];
  int d0 = blockIdx.x * 64, s0 = blockIdx.y * 64;
  int t = threadIdx.x;
  int tx = t & 63, ty = t >> 6;
  if (t < 64) invs[t] = invr[s0 + t];
  __syncthreads();
#pragma unroll
  for (int i = 0; i < 64; i += 4)
    tile[ty + i][tx] = (float)a3u[(size_t)(s0 + ty + i) * kN + d0 + tx] * invs[ty + i];
  __syncthreads();
#pragma unroll
  for (int i = 0; i < 64; i += 4)
    motifT[(size_t)(d0 + ty + i) * kN + s0 + tx] = tile[tx][ty + i];
}

// layer-1 GEMM, 32x64 tiles, register-prefetch double-buffered LDS,
// fused s_src/s_dst epilogue. grid (4, 64, 2)
__global__ __launch_bounds__(256) void gemm1(
    const float* __restrict__ x, const float* __restrict__ l1w,
    float* __restrict__ hx1,
    const float* __restrict__ l1as, const float* __restrict__ l1ad,
    float* __restrict__ ss1, float* __restrict__ sd1) {
  int hop = blockIdx.z;
  int row0 = blockIdx.y * 32, col0 = blockIdx.x * 64;
  const float* B = l1w + (size_t)hop * kIN * kC1;
  float* Cz = hx1 + (size_t)hop * kN * kC1;
  __shared__ float As[2][32][20];   // [buf][row][k]+pad, float4 ops
  __shared__ float Bs[2][16][68];   // [buf][k][col]+pad, float4 ops
  int t = threadIdx.x;
  int tx = t & 15, ty = t >> 4;
  int am = t >> 2, ak = (t & 3) * 4;     // A loader (threads 0-127)
  int bk = t >> 4, bn = (t & 15) * 4;    // B loader (all 256)
  float4 ra, rb;
  if (t < 128)
    ra = *reinterpret_cast<const float4*>(x + (size_t)(row0 + am) * kIN + ak);
  rb = *reinterpret_cast<const float4*>(B + (size_t)bk * kC1 + col0 + bn);
  if (t < 128)
    *reinterpret_cast<float4*>(&As[0][am][ak]) = ra;
  *reinterpret_cast<float4*>(&Bs[0][bk][bn]) = rb;
  __syncthreads();
  float acc[2][4] = {};
  int cur = 0;
  for (int k0 = 16; k0 <= kIN; k0 += 16) {
    bool more = (k0 < kIN);
    if (more) {
      if (t < 128)
        ra = *reinterpret_cast<const float4*>(x + (size_t)(row0 + am) * kIN + k0 + ak);
      rb = *reinterpret_cast<const float4*>(B + (size_t)(k0 + bk) * kC1 + col0 + bn);
    }
#pragma unroll
    for (int kk = 0; kk < 16; ++kk) {
      float a0 = As[cur][ty * 2 + 0][kk];
      float a1 = As[cur][ty * 2 + 1][kk];
      float4 b = *reinterpret_cast<const float4*>(&Bs[cur][kk][tx * 4]);
      acc[0][0] += a0 * b.x; acc[0][1] += a0 * b.y;
      acc[0][2] += a0 * b.z; acc[0][3] += a0 * b.w;
      acc[1][0] += a1 * b.x; acc[1][1] += a1 * b.y;
      acc[1][2] += a1 * b.z; acc[1][3] += a1 * b.w;
    }
    if (more) {
      if (t < 128)
        *reinterpret_cast<float4*>(&As[cur ^ 1][am][ak]) = ra;
      *reinterpret_cast<float4*>(&Bs[cur ^ 1][bk][bn]) = rb;
      __syncthreads();
      cur ^= 1;
    }
  }
#pragma unroll
  for (int i = 0; i < 2; ++i) {
    float4 c = make_float4(acc[i][0], acc[i][1], acc[i][2], acc[i][3]);
    *reinterpret_cast<float4*>(Cz + (size_t)(row0 + ty * 2 + i) * kC1 + col0 + tx * 4) = c;
  }
  int h = col0 >> 6;
  float as_[4], ad_[4];
#pragma unroll
  for (int j = 0; j < 4; ++j) {
    as_[j] = l1as[hop * kC1 + col0 + tx * 4 + j];
    ad_[j] = l1ad[hop * kC1 + col0 + tx * 4 + j];
  }
#pragma unroll
  for (int i = 0; i < 2; ++i) {
    float ps = acc[i][0] * as_[0] + acc[i][1] * as_[1] +
               acc[i][2] * as_[2] + acc[i][3] * as_[3];
    float pd = acc[i][0] * ad_[0] + acc[i][1] * ad_[1] +
               acc[i][2] * ad_[2] + acc[i][3] * ad_[3];
#pragma unroll
    for (int o = 1; o < 16; o <<= 1) {
      ps += __shfl_xor(ps, o);
      pd += __shfl_xor(pd, o);
    }
    if (tx == 0) {
      int n = row0 + ty * 2 + i;
      ss1[((size_t)hop * kN + n) * 4 + h] = ps;
      sd1[((size_t)hop * kN + n) * 4 + h] = pd;
    }
  }
}

// layer-2 GEMM, 16x64 tiles, dbuf (z: 0,1 = hops + src/dst epilogue; 2 = res).
// grid (1, 128, 3)
__global__ __launch_bounds__(256) void gemm2(
    const float* __restrict__ A, const float* __restrict__ l2w,
    const float* __restrict__ l2rw, float* __restrict__ C,
    const float* __restrict__ attS, const float* __restrict__ attD,
    float* __restrict__ ssO, float* __restrict__ sdO) {
  int z = blockIdx.z;
  const float* B = (z < 2) ? l2w + (size_t)z * kC1 * kC2 : l2rw;
  float* Cz = C + (size_t)z * kN * kC2;
  __shared__ float As[2][16][20];
  __shared__ float Bs[2][16][68];
  int t = threadIdx.x;
  int tx = t & 15, ty = t >> 4;  // ty = row
  int row0 = blockIdx.y * 16;
  int am = t >> 2, ak = (t & 3) * 4;     // A loader (threads 0-63)
  int bk = t >> 4, bn = (t & 15) * 4;    // B loader (all 256)
  float4 ra, rb;
  if (t < 64)
    ra = *reinterpret_cast<const float4*>(A + (size_t)(row0 + am) * kC1 + ak);
  rb = *reinterpret_cast<const float4*>(B + (size_t)bk * kC2 + bn);
  if (t < 64)
    *reinterpret_cast<float4*>(&As[0][am][ak]) = ra;
  *reinterpret_cast<float4*>(&Bs[0][bk][bn]) = rb;
  __syncthreads();
  float acc[4] = {};
  int cur = 0;
  for (int k0 = 16; k0 <= kC1; k0 += 16) {
    bool more = (k0 < kC1);
    if (more) {
      if (t < 64)
        ra = *reinterpret_cast<const float4*>(A + (size_t)(row0 + am) * kC1 + k0 + ak);
      rb = *reinterpret_cast<const float4*>(B + (size_t)(k0 + bk) * kC2 + bn);
    }
#pragma unroll
    for (int kk = 0; kk < 16; ++kk) {
      float a = As[cur][ty][kk];
      float4 b = *reinterpret_cast<const float4*>(&Bs[cur][kk][tx * 4]);
      acc[0] += a * b.x; acc[1] += a * b.y;
      acc[2] += a * b.z; acc[3] += a * b.w;
    }
    if (more) {
      if (t < 64)
        *reinterpret_cast<float4*>(&As[cur ^ 1][am][ak]) = ra;
      *reinterpret_cast<float4*>(&Bs[cur ^ 1][bk][bn]) = rb;
      __syncthreads();
      cur ^= 1;
    }
  }
  {
    float4 c = make_float4(acc[0], acc[1], acc[2], acc[3]);
    *reinterpret_cast<float4*>(Cz + (size_t)(row0 + ty) * kC2 + tx * 4) = c;
  }
  if (z < 2) {
    float as_[4], ad_[4];
#pragma unroll
    for (int j = 0; j < 4; ++j) {
      as_[j] = attS[z * kC2 + tx * 4 + j];
      ad_[j] = attD[z * kC2 + tx * 4 + j];
    }
    float ps = acc[0] * as_[0] + acc[1] * as_[1] + acc[2] * as_[2] + acc[3] * as_[3];
    float pd = acc[0] * ad_[0] + acc[1] * ad_[1] + acc[2] * ad_[2] + acc[3] * ad_[3];
#pragma unroll
    for (int o = 1; o < 16; o <<= 1) {
      ps += __shfl_xor(ps, o);
      pd += __shfl_xor(pd, o);
    }
    if (tx == 0) {
      int n = row0 + ty;
      ssO[(size_t)z * kN + n] = ps;
      sdO[(size_t)z * kN + n] = pd;
    }
  }
}

// layer-1 aggregation, fused stats; motifT row staged in LDS.
__global__ __launch_bounds__(256) void agg_l1(
    const float* __restrict__ hx,      // [2][N][256]
    const float* __restrict__ ssrc,    // [2][N][4]
    const float* __restrict__ sdst,    // [2][N][4]
    const float* __restrict__ motifT,  // [N(d)][N(s)]
    const unsigned long long* __restrict__ colbitsT,
    const unsigned long long* __restrict__ colbits2T,
    const float* __restrict__ hop_att,
    const float* __restrict__ bias,
    float* __restrict__ hbuf) {
  int d = blockIdx.x;
  int t = threadIdx.x;
  int lane = t & 63;
  int h = t >> 6;       // stats wave == head; also s-slot for FMA
  int cq = lane;        // channel quad [0,64)
  int hq = cq >> 4;     // head of this quad
  __shared__ unsigned short slist[kN];
  __shared__ float mrow[kN];
  __shared__ float w_lds[64 * 4];
  __shared__ int s_total;
  __shared__ float4 red4[4][64];
  {
    const float4* mp = reinterpret_cast<const float4*>(motifT + (size_t)d * kN);
    float4* mr = reinterpret_cast<float4*>(mrow);
    mr[t] = mp[t];
    mr[t + 256] = mp[t + 256];
  }
  float a0 = hop_att[0], a1 = hop_att[1];
  float mxa = fmaxf(a0, a1);
  float e0 = __expf(a0 - mxa), e1 = __expf(a1 - mxa);
  float wh0 = e0 / (e0 + e1), wh1 = e1 / (e0 + e1);
  float4 acc4 = make_float4(0.f, 0.f, 0.f, 0.f);
  for (int hop = 0; hop < 2; ++hop) {
    const unsigned long long* cm = hop ? colbits2T : colbitsT;
    if (t < 64) {
      unsigned long long word = (lane < kWords) ? cm[(size_t)lane * kN + d] : 0ull;
      if (lane == (d >> 6)) word |= 1ull << (d & 63);
      int cnt = __popcll(word);
      int inc = cnt;
      for (int o = 1; o < 64; o <<= 1) { int v = __shfl_up(inc, o); if (lane >= o) inc += v; }
      if (lane == 63) s_total = inc;
      int off = inc - cnt;
      int base = lane * 64;
      while (word) {
        int b = __builtin_ctzll(word);
        word &= word - 1;
        slist[off++] = (unsigned short)(base + b);
      }
    }
    __syncthreads();
    int total = s_total;
    float sd = sdst[((size_t)hop * kN + d) * 4 + h];
    const float4* hx4 = reinterpret_cast<const float4*>(hx + (size_t)hop * kN * kC1);
    const float* ssp = ssrc + (size_t)hop * kN * 4;
    float m1 = -3.0e38f, l1v = 0.f, m2 = -3.0e38f, l2v = 0.f;
    for (int q = lane; q < total; q += 64) {
      int s = slist[q];
      float mv = mrow[s];
      float v = ssp[s * 4 + h] + sd;
      onl(m1, l1v, leakyf(v));
      onl(m2, l2v, leakyf(v * mv));
    }
#pragma unroll
    for (int o = 1; o < 64; o <<= 1) {
      float mm = __shfl_xor(m1, o), ll = __shfl_xor(l1v, o);
      mergeml(m1, l1v, mm, ll);
      float mm2 = __shfl_xor(m2, o), ll2 = __shfl_xor(l2v, o);
      mergeml(m2, l2v, mm2, ll2);
    }
    float il1 = 1.f / l1v, il2 = 1.f / l2v;
    float wh = hop ? wh1 : wh0;
    for (int c0 = 0; c0 < total; c0 += 64) {
      int nsi = min(64, total - c0);
      if (lane < nsi) {
        int s = slist[c0 + lane];
        float mv = mrow[s];
        float v = ssp[s * 4 + h] + sd;
        w_lds[lane * 4 + h] = (0.5f * __expf(leakyf(v) - m1) * il1 +
                               0.5f * __expf(leakyf(v * mv) - m2) * il2) * wh;
      }
      __syncthreads();
      int q = h;
      for (; q + 4 < nsi; q += 8) {
        int s0 = slist[c0 + q], s1 = slist[c0 + q + 4];
        float4 r0 = hx4[(size_t)s0 * 64 + cq];
        float4 r1 = hx4[(size_t)s1 * 64 + cq];
        float w0 = w_lds[q * 4 + hq], w1 = w_lds[(q + 4) * 4 + hq];
        acc4.x += w0 * r0.x + w1 * r1.x;
        acc4.y += w0 * r0.y + w1 * r1.y;
        acc4.z += w0 * r0.z + w1 * r1.z;
        acc4.w += w0 * r0.w + w1 * r1.w;
      }
      if (q < nsi) {
        int s0 = slist[c0 + q];
        float4 r0 = hx4[(size_t)s0 * 64 + cq];
        float w0 = w_lds[q * 4 + hq];
        acc4.x += w0 * r0.x; acc4.y += w0 * r0.y;
        acc4.z += w0 * r0.z; acc4.w += w0 * r0.w;
      }
      __syncthreads();
    }
    __syncthreads();
  }
  red4[h][cq] = acc4;
  __syncthreads();
  if (t < 64) {
    float4 a = red4[0][t], b = red4[1][t], c = red4[2][t], e = red4[3][t];
    float4 bv = reinterpret_cast<const float4*>(bias)[t];
    float4 v;
    v.x = a.x + b.x + c.x + e.x + bv.x;
    v.y = a.y + b.y + c.y + e.y + bv.y;
    v.z = a.z + b.z + c.z + e.z + bv.z;
    v.w = a.w + b.w + c.w + e.w + bv.w;
    v.x = v.x > 0.f ? v.x : __expf(v.x) - 1.f;
    v.y = v.y > 0.f ? v.y : __expf(v.y) - 1.f;
    v.z = v.z > 0.f ? v.z : __expf(v.z) - 1.f;
    v.w = v.w > 0.f ? v.w : __expf(v.w) - 1.f;
    reinterpret_cast<float4*>(hbuf)[(size_t)d * 64 + t] = v;
  }
}

// layer-2 aggregation, fused stats; motifT row staged in LDS;
// fused residual + LayerNorm + bias -> output. grid = N.
__global__ __launch_bounds__(256) void agg_l2(
    const float* __restrict__ hx,      // [2][N][64]
    const float* __restrict__ ssrc,    // [2][N]
    const float* __restrict__ sdst,    // [2][N]
    const float* __restrict__ motifT,
    const unsigned long long* __restrict__ colbitsT,
    const unsigned long long* __restrict__ colbits2T,
    const float* __restrict__ hop_att,
    const float* __restrict__ res,     // [N][64]
    const float* __restrict__ lns, const float* __restrict__ lnb,
    const float* __restrict__ l2b,
    float* __restrict__ out) {
  int d = blockIdx.x;
  int t = threadIdx.x;
  int lane = t & 63;
  int g = t >> 6;      // wave id (stats)
  int cq = t & 15;     // channel quad [0,16)
  int sg = t >> 4;     // s-slot [0,16)
  __shared__ unsigned short slist[kN];
  __shared__ float mrow[kN];
  __shared__ float w_lds[64];
  __shared__ int s_total;
  __shared__ float4 red4[16][16];
  __shared__ float out_lds[64];
  __shared__ float smst[4][4];
  {
    const float4* mp = reinterpret_cast<const float4*>(motifT + (size_t)d * kN);
    float4* mr = reinterpret_cast<float4*>(mrow);
    mr[t] = mp[t];
    mr[t + 256] = mp[t + 256];
  }
  float a0 = hop_att[0], a1 = hop_att[1];
  float mxa = fmaxf(a0, a1);
  float e0 = __expf(a0 - mxa), e1 = __expf(a1 - mxa);
  float wh0 = e0 / (e0 + e1), wh1 = e1 / (e0 + e1);
  float4 acc4 = make_float4(0.f, 0.f, 0.f, 0.f);
  for (int hop = 0; hop < 2; ++hop) {
    const unsigned long long* cm = hop ? colbits2T : colbitsT;
    if (t < 64) {
      unsigned long long word = (lane < kWords) ? cm[(size_t)lane * kN + d] : 0ull;
      if (lane == (d >> 6)) word |= 1ull << (d & 63);
      int cnt = __popcll(word);
      int inc = cnt;
      for (int o = 1; o < 64; o <<= 1) { int v = __shfl_up(inc, o); if (lane >= o) inc += v; }
      if (lane == 63) s_total = inc;
      int off = inc - cnt;
      int base = lane * 64;
      while (word) {
        int b = __builtin_ctzll(word);
        word &= word - 1;
        slist[off++] = (unsigned short)(base + b);
      }
    }
    __syncthreads();
    int total = s_total;
    float sd = sdst[(size_t)hop * kN + d];
    const float4* hx4 = reinterpret_cast<const float4*>(hx + (size_t)hop * kN * kC2);
    const float* ssp = ssrc + (size_t)hop * kN;
    float m1 = -3.0e38f, l1v = 0.f, m2 = -3.0e38f, l2v = 0.f;
    for (int q = t; q < total; q += 256) {
      int s = slist[q];
      float mv = mrow[s];
      float v = ssp[s] + sd;
      onl(m1, l1v, leakyf(v));
      onl(m2, l2v, leakyf(v * mv));
    }
#pragma unroll
    for (int o = 1; o < 64; o <<= 1) {
      float mm = __shfl_xor(m1, o), ll = __shfl_xor(l1v, o);
      mergeml(m1, l1v, mm, ll);
      float mm2 = __shfl_xor(m2, o), ll2 = __shfl_xor(l2v, o);
      mergeml(m2, l2v, mm2, ll2);
    }
    if (lane == 0) {
      smst[g][0] = m1; smst[g][1] = l1v; smst[g][2] = m2; smst[g][3] = l2v;
    }
    __syncthreads();
    float M1 = -3.0e38f, L1 = 0.f, M2 = -3.0e38f, L2 = 0.f;
#pragma unroll
    for (int gg = 0; gg < 4; ++gg) {
      mergeml(M1, L1, smst[gg][0], smst[gg][1]);
      mergeml(M2, L2, smst[gg][2], smst[gg][3]);
    }
    float il1 = 1.f / L1, il2 = 1.f / L2;
    float wh = hop ? wh1 : wh0;
    for (int c0 = 0; c0 < total; c0 += 64) {
      int nsi = min(64, total - c0);
      if (t < nsi) {
        int s = slist[c0 + t];
        float mv = mrow[s];
        float v = ssp[s] + sd;
        w_lds[t] = (0.5f * __expf(leakyf(v) - M1) * il1 +
                    0.5f * __expf(leakyf(v * mv) - M2) * il2) * wh;
      }
      __syncthreads();
      int q = sg;
      for (; q + 16 < nsi; q += 32) {
        int s0 = slist[c0 + q], s1 = slist[c0 + q + 16];
        float4 r0 = hx4[(size_t)s0 * 16 + cq];
        float4 r1 = hx4[(size_t)s1 * 16 + cq];
        float w0 = w_lds[q], w1 = w_lds[q + 16];
        acc4.x += w0 * r0.x + w1 * r1.x;
        acc4.y += w0 * r0.y + w1 * r1.y;
        acc4.z += w0 * r0.z + w1 * r1.z;
        acc4.w += w0 * r0.w + w1 * r1.w;
      }
      if (q < nsi) {
        int s0 = slist[c0 + q];
        float4 r0 = hx4[(size_t)s0 * 16 + cq];
        float w0 = w_lds[q];
        acc4.x += w0 * r0.x; acc4.y += w0 * r0.y;
        acc4.z += w0 * r0.z; acc4.w += w0 * r0.w;
      }
      __syncthreads();
    }
    __syncthreads();
  }
  red4[sg][cq] = acc4;
  __syncthreads();
  if (t < 16) {
    float4 v = make_float4(0.f, 0.f, 0.f, 0.f);
#pragma unroll
    for (int q = 0; q < 16; ++q) {
      float4 a = red4[q][t];
      v.x += a.x; v.y += a.y; v.z += a.z; v.w += a.w;
    }
    out_lds[t * 4 + 0] = v.x;
    out_lds[t * 4 + 1] = v.y;
    out_lds[t * 4 + 2] = v.z;
    out_lds[t * 4 + 3] = v.w;
  }
  __syncthreads();
  if (t < 64) {
    float v = out_lds[t] + res[(size_t)d * kC2 + t];
    float s = v;
    for (int o = 32; o; o >>= 1) s += __shfl_xor(s, o);
    float mu = s * (1.f / kC2);
    float dv = v - mu;
    float q = dv * dv;
    for (int o = 32; o; o >>= 1) q += __shfl_xor(q, o);
    float var = q * (1.f / kC2);
    out[(size_t)d * kC2 + t] = dv * rsqrtf(var + kLnEps) * lns[t] + lnb[t] + l2b[t];
  }
}

}  // namespace

extern "C" void kernel_launch(void* const* d_in, const int* in_sizes, int n_in,
                              void* d_out, int out_size, void* d_ws, size_t ws_size,
                              hipStream_t stream) {
  const float* x    = (const float*)d_in[0];
  const int*   ei   = (const int*)d_in[1];
  const float* l1w  = (const float*)d_in[2];
  const float* l1as = (const float*)d_in[3];
  const float* l1ad = (const float*)d_in[4];
  const float* l1ha = (const float*)d_in[5];
  const float* l1b  = (const float*)d_in[6];
  const float* l2w  = (const float*)d_in[7];
  const float* l2as = (const float*)d_in[8];
  const float* l2ad = (const float*)d_in[9];
  const float* l2ha = (const float*)d_in[10];
  const float* l2rw = (const float*)d_in[11];
  const float* lns  = (const float*)d_in[12];
  const float* lnb  = (const float*)d_in[13];
  const float* l2b  = (const float*)d_in[14];
  int E = in_sizes[1] / 2;

  // ---- workspace layout (bytes) ----
  size_t o = 0;
  auto take = [&](size_t bytes) { size_t r = o; o += (bytes + 255) & ~(size_t)255; return r; };
  size_t oRB  = take((size_t)kN * kWords * 8);      // rowbits (zeroed)
  size_t oCB  = take((size_t)kWords * kN * 8);      // colbitsT (zeroed)
  size_t zEnd = o;                                  // zero region end
  size_t oCB2 = take((size_t)kWords * kN * 8);      // colbits2T (fully written)
  size_t oA2  = take((size_t)kN * kN * 2);          // dense A2 u16
  size_t oA3  = take((size_t)kN * kN * 2);          // dense A3 u16 (unnormalized)
  size_t oINV = take((size_t)kN * 4);               // 1/rowsum
  size_t oMFT = take((size_t)kN * kN * 4);          // motifT f32
  size_t oHX1 = take((size_t)2 * kN * kC1 * 4);
  size_t oH   = take((size_t)kN * kC1 * 4);
  size_t oHX2 = take((size_t)3 * kN * kC2 * 4);     // hop0 | hop1 | res
  size_t oSS1 = take((size_t)2 * kN * 4 * 4);
  size_t oSD1 = take((size_t)2 * kN * 4 * 4);
  size_t oSS2 = take((size_t)2 * kN * 4);
  size_t oSD2 = take((size_t)2 * kN * 4);
  if (ws_size < o) return;  // insufficient scratch; fail visibly

  char* w = (char*)d_ws;
  unsigned long long* rowbits = (unsigned long long*)(w + oRB);
  unsigned long long* colbitsT = (unsigned long long*)(w + oCB);
  unsigned long long* colbits2T = (unsigned long long*)(w + oCB2);
  unsigned short* A2 = (unsigned short*)(w + oA2);
  unsigned short* A3u = (unsigned short*)(w + oA3);
  float* invr = (float*)(w + oINV);
  float* motifT = (float*)(w + oMFT);
  float* hx1 = (float*)(w + oHX1);
  float* hbuf = (float*)(w + oH);
  float* hx2 = (float*)(w + oHX2);
  float* res = hx2 + (size_t)2 * kN * kC2;
  float* ss1 = (float*)(w + oSS1);
  float* sd1 = (float*)(w + oSD1);
  float* ss2 = (float*)(w + oSS2);
  float* sd2 = (float*)(w + oSD2);

  hipMemsetAsync(d_ws, 0, zEnd, stream);

  build_bits<<<(E + 255) / 256, 256, 0, stream>>>(ei, E, rowbits, colbitsT);
  a2_tiled<<<dim3(kN / 64, kN / 64), 256, 0, stream>>>(rowbits, colbitsT, A2, colbits2T);
  a3_dense<<<kN, 256, 0, stream>>>(rowbits, A2, A3u, invr);
  transpose_motif<<<dim3(kN / 64, kN / 64), 256, 0, stream>>>(A3u, invr, motifT);

  gemm1<<<dim3(kC1 / 64, kN / 32, 2), 256, 0, stream>>>(x, l1w, hx1, l1as, l1ad, ss1, sd1);
  agg_l1<<<kN, 256, 0, stream>>>(hx1, ss1, sd1, motifT, colbitsT, colbits2T,
                                 l1ha, l1b, hbuf);

  gemm2<<<dim3(1, kN / 16, 3), 256, 0, stream>>>(hbuf, l2w, l2rw, hx2,
                                                 l2as, l2ad, ss2, sd2);
  agg_l2<<<kN, 256, 0, stream>>>(hx2, ss2, sd2, motifT, colbitsT, colbits2T,
                                 l2ha, res, lns, lnb, l2b, (float*)d_out);
}